// Round 5
// baseline (7850.602 us; speedup 1.0000x reference)
//
#include <hip/hip_runtime.h>
#include <cstdint>

typedef __attribute__((ext_vector_type(8))) short short8;
typedef __attribute__((ext_vector_type(4))) float f32x4;
typedef __attribute__((ext_vector_type(4))) unsigned int u32x4;

#define L_ 256
#define E_ 512
#define H_ 512
#define TH_ 1536

#define PACK_PER_CS 24576                    // ushorts per (mat, cs): 16 ks * 3 f * 64 lanes * 8
#define PACK_TOTAL (8 * 32 * PACK_PER_CS)    // 6,291,456 ushorts
#define HPUB_OFF ((size_t)PACK_TOTAL * 2)    // bytes into ws
#define HPUB_DWORDS (2 * 8 * 32 * 512)       // [buf][group][row32][k512] tagged dwords (512 KB)

#define BAIL_TICKS 10000000ULL               // ~0.1 s at 100 MHz ref clock

__device__ __forceinline__ unsigned short f2bf(float v) {
    unsigned int u = __builtin_bit_cast(unsigned int, v);
    u += 0x7FFFu + ((u >> 16) & 1u);
    return (unsigned short)(u >> 16);
}
__device__ __forceinline__ float sigm_(float x) { return 1.f / (1.f + __expf(-x)); }
__device__ __forceinline__ float tanh_(float x) {
    float e = __expf(2.f * x);
    return 1.f - 2.f / (e + 1.f);
}

// Pack all 8 weight matrices ([512 x 1536] each) into per-(mat, colslice) MFMA
// fragment layout: elem idx = ((((mat*32+cs)*16 + ks)*3 + f)*64 + lane)*8 + e
// holds U[k][col] with k = ks*32 + (lane>>4)*8 + e, col = f*512 + cs*16 + (lane&15).
__global__ void pack_weights(const float* __restrict__ fWx, const float* __restrict__ fUh,
                             const float* __restrict__ ftU, const float* __restrict__ bWx,
                             const float* __restrict__ bUh, const float* __restrict__ btU,
                             unsigned short* __restrict__ pack) {
    unsigned int idx = blockIdx.x * 256u + threadIdx.x;
    if (idx >= (unsigned)PACK_TOTAL) return;
    int e = idx & 7;
    int l = (idx >> 3) & 63;
    unsigned int r = idx >> 9;
    int f = r % 3; r /= 3;
    int ks = r & 15; r >>= 4;
    int cs = r & 31; r >>= 5;
    int m = r;  // 0..7: {f_Wx, f_Uh, f_tU0, f_tU1, b_Wx, b_Uh, b_tU0, b_tU1}
    int k = ks * 32 + (l >> 4) * 8 + e;
    int col = f * 512 + cs * 16 + (l & 15);
    const float* src;
    switch (m) {
        case 0: src = fWx; break;
        case 1: src = fUh; break;
        case 2: src = ftU; break;
        case 3: src = ftU + H_ * TH_; break;
        case 4: src = bWx; break;
        case 5: src = bUh; break;
        case 6: src = btU; break;
        default: src = btU + H_ * TH_; break;
    }
    pack[idx] = f2bf(src[(size_t)k * TH_ + col]);
}

// Cheap gate, own-cohort rows, monotone >=. Fast path: sc0 (XCD-local L2).
// Escalation: sc0 sc1 (MALL) — placement-independent correctness.
__device__ __forceinline__ void poll_tag(const unsigned int* sp, unsigned int tag, bool* dead) {
    if (*dead) return;
    for (int it = 0; it < 64; ++it) {
        unsigned int v;
        asm volatile("global_load_dword %0, %1, off sc0" : "=v"(v) : "v"(sp) : "memory");
        asm volatile("s_waitcnt vmcnt(0)" ::: "memory");
        __builtin_amdgcn_sched_barrier(0);
        if (__all((int)((v >> 16) >= tag))) return;
    }
    unsigned long long t0 = __builtin_amdgcn_s_memrealtime();
    while (true) {
        unsigned int v;
        asm volatile("global_load_dword %0, %1, off sc0 sc1" : "=v"(v) : "v"(sp) : "memory");
        asm volatile("s_waitcnt vmcnt(0)" ::: "memory");
        __builtin_amdgcn_sched_barrier(0);
        if (__all((int)((v >> 16) >= tag))) return;
        if (__builtin_amdgcn_s_memrealtime() - t0 > BAIL_TICKS) { *dead = true; return; }
    }
}

template <bool SYS>
__device__ __forceinline__ void ld32(const unsigned int* base, u32x4* D) {
#pragma unroll
    for (int i = 0; i < 32; ++i) {
        if constexpr (SYS)
            asm volatile("global_load_dwordx4 %0, %1, off offset:%c2 sc0 sc1"
                         : "=v"(D[i]) : "v"(base), "i"(((i >> 1) * 128) + ((i & 1) * 16)) : "memory");
        else
            asm volatile("global_load_dwordx4 %0, %1, off offset:%c2 sc0"
                         : "=v"(D[i]) : "v"(base), "i"(((i >> 1) * 128) + ((i & 1) * 16)) : "memory");
    }
    asm volatile("s_waitcnt vmcnt(0)" ::: "memory");
    __builtin_amdgcn_sched_barrier(0);
}

__device__ __forceinline__ bool chk(const u32x4* D, unsigned int ehi) {
    unsigned int acc = 0;
#pragma unroll
    for (int i = 0; i < 32; ++i) {
#pragma unroll
        for (int e = 0; e < 4; ++e) acc |= D[i][e] ^ ehi;
    }
    return __all((int)((acc & 0xFFFF0000u) == 0u));
}

// Bulk tagged h load: 32x dwordx4 (128 tagged words/lane), verify every tag ==.
// Rows form a closed wave-index cohort => exact-tag verify is deadlock-free.
// vmcnt(0) drains our own prior epilogue stores -> same-address store ordering.
__device__ __forceinline__ void load_htag(const unsigned int* base, unsigned int tag, u32x4* D,
                                          bool* dead) {
    const unsigned int ehi = tag << 16;
    for (int it = 0; it < 3; ++it) {
        ld32<false>(base, D);
        if (chk(D, ehi)) return;
        if (*dead) break;
    }
    if (!*dead) {
        unsigned long long t0 = __builtin_amdgcn_s_memrealtime();
        while (true) {
            ld32<true>(base, D);
            if (chk(D, ehi)) return;
            if (__builtin_amdgcn_s_memrealtime() - t0 > BAIL_TICKS) { *dead = true; break; }
            __builtin_amdgcn_s_sleep(1);
        }
    }
    // poison with bf16 NaN so a protocol flaw fails LOUDLY and fast
    const unsigned int p = ehi | 0x7FC0u;
#pragma unroll
    for (int i = 0; i < 32; ++i) { D[i][0] = p; D[i][1] = p; D[i][2] = p; D[i][3] = p; }
}

// Pack 8 tagged dwords (lo16 = bf16 h) into one MFMA A-fragment.
__device__ __forceinline__ short8 pack_a(const u32x4& d0, const u32x4& d1) {
    u32x4 r;
    r[0] = __builtin_amdgcn_perm(d0[1], d0[0], 0x05040100u);
    r[1] = __builtin_amdgcn_perm(d0[3], d0[2], 0x05040100u);
    r[2] = __builtin_amdgcn_perm(d1[1], d1[0], 0x05040100u);
    r[3] = __builtin_amdgcn_perm(d1[3], d1[2], 0x05040100u);
    return __builtin_bit_cast(short8, r);
}

__device__ __forceinline__ void st_tag(unsigned int* p, unsigned int v) {
    asm volatile("global_store_dword %0, %1, off sc0 sc1" :: "v"(p), "v"(v) : "memory");
}

// One transition GRU cell (gx = bias only). rc0g = C-row base within group buffer.
__device__ __forceinline__ void trans_cell(const unsigned int* hbase, const unsigned int* spp,
                                           unsigned int tag, const unsigned short* ldsp,
                                           int lane, float br, float bz, float bhh,
                                           const float* mm, float* hreg, unsigned int* hwr,
                                           int rc0g, int hcol, bool* dead) {
    poll_tag(spp, tag, dead);
    u32x4 D[32];
    load_htag(hbase, tag, D, dead);
    f32x4 acc0 = {0.f, 0.f, 0.f, 0.f}, acc1 = acc0, acc2 = acc0;
#pragma unroll
    for (int ks = 0; ks < 16; ++ks) {
        short8 A = pack_a(D[2 * ks], D[2 * ks + 1]);
        short8 B0 = *(const short8*)(ldsp + (ks * 3 + 0) * 512 + lane * 8);
        short8 B1 = *(const short8*)(ldsp + (ks * 3 + 1) * 512 + lane * 8);
        short8 B2 = *(const short8*)(ldsp + (ks * 3 + 2) * 512 + lane * 8);
        acc0 = __builtin_amdgcn_mfma_f32_16x16x32_bf16(A, B0, acc0, 0, 0, 0);
        acc1 = __builtin_amdgcn_mfma_f32_16x16x32_bf16(A, B1, acc1, 0, 0, 0);
        acc2 = __builtin_amdgcn_mfma_f32_16x16x32_bf16(A, B2, acc2, 0, 0, 0);
    }
    const unsigned int ptag = (tag + 1) << 16;
#pragma unroll
    for (int j = 0; j < 4; ++j) {
        float r = sigm_(acc0[j] + br);
        float z = sigm_(acc1[j] + bz);
        float ht = tanh_(bhh + r * acc2[j]);
        float hn = (1.f - z) * ht + z * hreg[j];
        hn = mm[j] * hn + (1.f - mm[j]) * hreg[j];
        hreg[j] = hn;
        st_tag(hwr + (rc0g + j) * 512 + hcol, ptag | (unsigned int)f2bf(hn));
    }
}

// 256 WGs x 128 threads. group = wg % 8 (presumed XCD via round-robin dispatch),
// cs = wg / 8. Group = (dir, batch-quarter of 32 rows); all h exchange stays
// within the group => XCD-local L2 fast path, MALL escalation for safety.
__global__ __launch_bounds__(128, 1) void rnn_kernel(
    const float* __restrict__ xs, const float* __restrict__ xmask,
    const float* __restrict__ fb, const float* __restrict__ bb,
    const float* __restrict__ ftb, const float* __restrict__ btb,
    float* __restrict__ out, const unsigned short* __restrict__ pack,
    unsigned int* __restrict__ hpub32) {
    extern __shared__ unsigned short lds_u16[];
    const int tid = threadIdx.x;
    const int wg = blockIdx.x;     // 0..255
    const int g = wg & 7;          // group (presumed XCD)
    const int cs = wg >> 3;        // column slice 0..31
    const int dir = g >> 2;        // 0 fwd, 1 bwd
    const int qb = g & 3;          // batch quarter: rows [qb*32, qb*32+32)
    const int w = tid >> 6;        // wave 0..1 -> 16-row block within quarter
    const int lane = tid & 63;

    // Load resident weight packs (Uh, tU0, tU1 slices) into LDS: 3 x 49152 B.
    for (int m = 0; m < 3; ++m) {
        const u32x4* src = (const u32x4*)(pack + (size_t)((dir * 4 + 1 + m) * 32 + cs) * PACK_PER_CS);
        u32x4* dst = (u32x4*)(lds_u16 + m * PACK_PER_CS);
        for (int i = tid; i < PACK_PER_CS / 8; i += 128) dst[i] = src[i];
    }
    __syncthreads();

    const int c16 = lane & 15;
    const int kg = lane >> 4;
    const int rowAg = w * 16 + c16;        // A row within group (0..31)
    const int rc0g = w * 16 + kg * 4;      // C row base within group
    const int rowA = qb * 32 + rowAg;      // global batch row (A)
    const int rowC0 = qb * 32 + rc0g;      // global batch row (C base)
    const int hcol = cs * 16 + c16;

    const float* bsrc = dir ? bb : fb;
    const float* tbsrc = dir ? btb : ftb;
    const float b0r = bsrc[hcol], b0z = bsrc[512 + hcol], b0h = bsrc[1024 + hcol];
    const float b1r = tbsrc[hcol], b1z = tbsrc[512 + hcol], b1h = tbsrc[1024 + hcol];
    const float b2r = tbsrc[TH_ + hcol], b2z = tbsrc[TH_ + 512 + hcol], b2h = tbsrc[TH_ + 1024 + hcol];

    float hreg[4] = {0.f, 0.f, 0.f, 0.f};
    bool dead = false;

    const unsigned short* wxpack =
        pack + (size_t)((dir * 4 + 0) * 32 + cs) * PACK_PER_CS + lane * 8;
    unsigned int* hb0 = hpub32 + g * 32 * 512;
    unsigned int* hb1 = hpub32 + 8 * 32 * 512 + g * 32 * 512;
    const int ka = kg * 8;
    const int aoff = rowAg * 512 + ka;     // dword offset within group buffer
    const float* xrow = xs + (size_t)rowA * L_ * E_ + ka;

    // Cheap-poll sample from OWN wave cohort's rows: wave w samples rows w*16+3
    // (kg=0 last store) / w*16+15 (kg=3 last store), producer cs = lane&31.
    const int sp_hi = lane >> 5;
    const int sp_off = (w * 16 + (sp_hi ? 15 : 3)) * 512 + (lane & 31) * 16 + (sp_hi ? 15 : 0);

    unsigned int gcnt = 0;  // cell counter; read tag = gcnt (0 = pre-zeroed h0), publish gcnt+1
    for (int s = 0; s < L_; ++s) {
        const int t = dir ? (L_ - 1 - s) : s;
        float mm[4];
#pragma unroll
        for (int j = 0; j < 4; ++j) mm[j] = xmask[(rowC0 + j) * L_ + t];

        // ---- CELL 0 x-part (h-independent): overlaps predecessors' publishes ----
        f32x4 acc0 = {0.f, 0.f, 0.f, 0.f}, acc1 = acc0, accgx = acc0;
        {
            const float* xp = xrow + (size_t)t * E_;
#pragma unroll
            for (int ks = 0; ks < 16; ++ks) {
                f32x4 x0 = *(const f32x4*)(xp + ks * 32);
                f32x4 x1 = *(const f32x4*)(xp + ks * 32 + 4);
                short8 A2;
#pragma unroll
                for (int e = 0; e < 4; ++e) {
                    A2[e] = (short)f2bf(x0[e]);
                    A2[4 + e] = (short)f2bf(x1[e]);
                }
                short8 W0 = *(const short8*)(wxpack + (ks * 3 + 0) * 512);
                short8 W1 = *(const short8*)(wxpack + (ks * 3 + 1) * 512);
                short8 W2 = *(const short8*)(wxpack + (ks * 3 + 2) * 512);
                acc0 = __builtin_amdgcn_mfma_f32_16x16x32_bf16(A2, W0, acc0, 0, 0, 0);
                acc1 = __builtin_amdgcn_mfma_f32_16x16x32_bf16(A2, W1, acc1, 0, 0, 0);
                accgx = __builtin_amdgcn_mfma_f32_16x16x32_bf16(A2, W2, accgx, 0, 0, 0);
            }
        }
        // ---- CELL 0 h-part ----
        {
            const unsigned int* hbcur = (gcnt & 1) ? hb1 : hb0;
            unsigned int* hwr = (gcnt & 1) ? hb0 : hb1;
            poll_tag(hbcur + sp_off, gcnt, &dead);
            u32x4 D[32];
            load_htag(hbcur + aoff, gcnt, D, &dead);
            f32x4 accgh = {0.f, 0.f, 0.f, 0.f};
#pragma unroll
            for (int ks = 0; ks < 16; ++ks) {
                short8 A = pack_a(D[2 * ks], D[2 * ks + 1]);
                short8 B0 = *(const short8*)(lds_u16 + (ks * 3 + 0) * 512 + lane * 8);
                short8 B1 = *(const short8*)(lds_u16 + (ks * 3 + 1) * 512 + lane * 8);
                short8 B2 = *(const short8*)(lds_u16 + (ks * 3 + 2) * 512 + lane * 8);
                acc0 = __builtin_amdgcn_mfma_f32_16x16x32_bf16(A, B0, acc0, 0, 0, 0);
                acc1 = __builtin_amdgcn_mfma_f32_16x16x32_bf16(A, B1, acc1, 0, 0, 0);
                accgh = __builtin_amdgcn_mfma_f32_16x16x32_bf16(A, B2, accgh, 0, 0, 0);
            }
            const unsigned int ptag = (gcnt + 1) << 16;
#pragma unroll
            for (int j = 0; j < 4; ++j) {
                float r = sigm_(acc0[j] + b0r);
                float z = sigm_(acc1[j] + b0z);
                float ht = tanh_(accgx[j] + b0h + r * accgh[j]);
                float hn = (1.f - z) * ht + z * hreg[j];
                hn = mm[j] * hn + (1.f - mm[j]) * hreg[j];
                hreg[j] = hn;
                st_tag(hwr + (rc0g + j) * 512 + hcol, ptag | (unsigned int)f2bf(hn));
            }
        }
        gcnt++;
        // ---- CELL 1 (TGRU 0) ----
        trans_cell(((gcnt & 1) ? hb1 : hb0) + aoff, ((gcnt & 1) ? hb1 : hb0) + sp_off, gcnt,
                   lds_u16 + PACK_PER_CS, lane, b1r, b1z, b1h, mm, hreg,
                   (gcnt & 1) ? hb0 : hb1, rc0g, hcol, &dead);
        gcnt++;
        // ---- CELL 2 (TGRU 1) ----
        trans_cell(((gcnt & 1) ? hb1 : hb0) + aoff, ((gcnt & 1) ? hb1 : hb0) + sp_off, gcnt,
                   lds_u16 + 2 * PACK_PER_CS, lane, b2r, b2z, b2h, mm, hreg,
                   (gcnt & 1) ? hb0 : hb1, rc0g, hcol, &dead);
        gcnt++;
#pragma unroll
        for (int j = 0; j < 4; ++j) {
            out[(size_t)((rowC0 + j) * L_ + t) * 1024 + dir * 512 + hcol] = mm[j] * hreg[j];
        }
    }
}

extern "C" void kernel_launch(void* const* d_in, const int* in_sizes, int n_in, void* d_out,
                              int out_size, void* d_ws, size_t ws_size, hipStream_t stream) {
    (void)in_sizes; (void)n_in; (void)out_size; (void)ws_size;
    const float* xs = (const float*)d_in[0];
    const float* xmask = (const float*)d_in[1];
    const float* fWx = (const float*)d_in[2];
    const float* fUh = (const float*)d_in[3];
    const float* fb = (const float*)d_in[4];
    const float* bWx = (const float*)d_in[5];
    const float* bUh = (const float*)d_in[6];
    const float* bb = (const float*)d_in[7];
    const float* ftU = (const float*)d_in[8];
    const float* ftb = (const float*)d_in[9];
    const float* btU = (const float*)d_in[10];
    const float* btb = (const float*)d_in[11];

    unsigned short* pack = (unsigned short*)d_ws;
    unsigned int* hpub32 = (unsigned int*)((char*)d_ws + HPUB_OFF);

    // zero tagged h buffers (tag 0 == initial h0 == 0.0f); re-runs on every graph replay
    hipMemsetAsync((char*)d_ws + HPUB_OFF, 0, (size_t)HPUB_DWORDS * 4, stream);

    pack_weights<<<PACK_TOTAL / 256, 256, 0, stream>>>(fWx, fUh, ftU, bWx, bUh, btU, pack);

    hipFuncSetAttribute((const void*)rnn_kernel, hipFuncAttributeMaxDynamicSharedMemorySize,
                        3 * PACK_PER_CS * 2);

    rnn_kernel<<<256, 128, 3 * PACK_PER_CS * 2, stream>>>(xs, xmask, fb, bb, ftb, btb,
                                                          (float*)d_out, pack, hpub32);
}

// Round 6
// 6662.421 us; speedup vs baseline: 1.1783x; 1.1783x over previous
//
#include <hip/hip_runtime.h>
#include <cstdint>

typedef __attribute__((ext_vector_type(8))) short short8;
typedef __attribute__((ext_vector_type(4))) float f32x4;
typedef __attribute__((ext_vector_type(4))) unsigned int u32x4;

#define L_ 256
#define E_ 512
#define H_ 512
#define TH_ 1536

#define PACK_PER_CS 24576                    // ushorts per (mat, cs): 16 ks * 3 f * 64 lanes * 8
#define PACK_TOTAL (8 * 32 * PACK_PER_CS)    // 6,291,456 ushorts
#define HPUB_OFF ((size_t)PACK_TOTAL * 2)    // bytes into ws
#define GRP_DW 16384                         // 32 rows * 512 cols dwords per group per buf
#define BUF_DW (8 * GRP_DW)                  // per buffer: 131,072 dwords
#define COPY_DW (2 * BUF_DW)                 // per copy (2 bufs): 262,144 dwords (1 MB)
// layout: [loc: 2 bufs][sys: 2 bufs] -> 2 MB total

#define BAIL_TICKS 10000000ULL               // ~0.1 s at 100 MHz ref clock
#define LOC_GATE_BUDGET 512                  // stale local polls before latching to sys
#define LOC_BULK_BUDGET 8                    // stale local bulk attempts before latching

__device__ __forceinline__ unsigned short f2bf(float v) {
    unsigned int u = __builtin_bit_cast(unsigned int, v);
    u += 0x7FFFu + ((u >> 16) & 1u);
    return (unsigned short)(u >> 16);
}
__device__ __forceinline__ float sigm_(float x) { return 1.f / (1.f + __expf(-x)); }
__device__ __forceinline__ float tanh_(float x) {
    float e = __expf(2.f * x);
    return 1.f - 2.f / (e + 1.f);
}

// Pack all 8 weight matrices ([512 x 1536] each) into per-(mat, colslice) MFMA
// fragment layout: elem idx = ((((mat*32+cs)*16 + ks)*3 + f)*64 + lane)*8 + e
// holds U[k][col] with k = ks*32 + (lane>>4)*8 + e, col = f*512 + cs*16 + (lane&15).
__global__ void pack_weights(const float* __restrict__ fWx, const float* __restrict__ fUh,
                             const float* __restrict__ ftU, const float* __restrict__ bWx,
                             const float* __restrict__ bUh, const float* __restrict__ btU,
                             unsigned short* __restrict__ pack) {
    unsigned int idx = blockIdx.x * 256u + threadIdx.x;
    if (idx >= (unsigned)PACK_TOTAL) return;
    int e = idx & 7;
    int l = (idx >> 3) & 63;
    unsigned int r = idx >> 9;
    int f = r % 3; r /= 3;
    int ks = r & 15; r >>= 4;
    int cs = r & 31; r >>= 5;
    int m = r;  // 0..7: {f_Wx, f_Uh, f_tU0, f_tU1, b_Wx, b_Uh, b_tU0, b_tU1}
    int k = ks * 32 + (l >> 4) * 8 + e;
    int col = f * 512 + cs * 16 + (l & 15);
    const float* src;
    switch (m) {
        case 0: src = fWx; break;
        case 1: src = fUh; break;
        case 2: src = ftU; break;
        case 3: src = ftU + H_ * TH_; break;
        case 4: src = bWx; break;
        case 5: src = bUh; break;
        case 6: src = btU; break;
        default: src = btU + H_ * TH_; break;
    }
    pack[idx] = f2bf(src[(size_t)k * TH_ + col]);
}

// Cheap gate, own-cohort rows, monotone >=.
// mode 0 (local): sc0 loads -> XCD L2. Producer's PLAIN stores update the L2
// line in place, so a stale hit turns fresh as soon as the producer lands.
// mode 1 (sys): sc0 sc1 loads -> MALL (placement-independent).
__device__ __forceinline__ void poll_tag(const unsigned int* spl, const unsigned int* sps,
                                         unsigned int tag, int* mode, bool* dead) {
    if (*dead) return;
    if (*mode == 0) {
        for (int it = 0; it < LOC_GATE_BUDGET; ++it) {
            unsigned int v;
            asm volatile("global_load_dword %0, %1, off sc0" : "=v"(v) : "v"(spl) : "memory");
            asm volatile("s_waitcnt vmcnt(0)" ::: "memory");
            __builtin_amdgcn_sched_barrier(0);
            if (__all((int)((v >> 16) >= tag))) return;
        }
        *mode = 1;  // group not co-resident on one XCD -> permanent sys latch
    }
    unsigned long long t0 = __builtin_amdgcn_s_memrealtime();
    while (true) {
        unsigned int v;
        asm volatile("global_load_dword %0, %1, off sc0 sc1" : "=v"(v) : "v"(sps) : "memory");
        asm volatile("s_waitcnt vmcnt(0)" ::: "memory");
        __builtin_amdgcn_sched_barrier(0);
        if (__all((int)((v >> 16) >= tag))) return;
        if (__builtin_amdgcn_s_memrealtime() - t0 > BAIL_TICKS) { *dead = true; return; }
    }
}

template <bool SYS>
__device__ __forceinline__ void ld32(const unsigned int* base, u32x4* D) {
#pragma unroll
    for (int i = 0; i < 32; ++i) {
        if constexpr (SYS)
            asm volatile("global_load_dwordx4 %0, %1, off offset:%c2 sc0 sc1"
                         : "=v"(D[i]) : "v"(base), "i"(((i >> 1) * 128) + ((i & 1) * 16)) : "memory");
        else
            asm volatile("global_load_dwordx4 %0, %1, off offset:%c2 sc0"
                         : "=v"(D[i]) : "v"(base), "i"(((i >> 1) * 128) + ((i & 1) * 16)) : "memory");
    }
    asm volatile("s_waitcnt vmcnt(0)" ::: "memory");
    __builtin_amdgcn_sched_barrier(0);
}

__device__ __forceinline__ bool chk(const u32x4* D, unsigned int ehi) {
    unsigned int acc = 0;
#pragma unroll
    for (int i = 0; i < 32; ++i) {
#pragma unroll
        for (int e = 0; e < 4; ++e) acc |= D[i][e] ^ ehi;
    }
    return __all((int)((acc & 0xFFFF0000u) == 0u));
}

// Bulk tagged h load (32x dwordx4 = 128 tagged words/lane), exact-tag verify.
// Rows form a closed wave-index cohort => exact verify is deadlock-free.
// vmcnt(0) drains our own prior epilogue stores -> same-slot store ordering.
__device__ __forceinline__ void load_htag(const unsigned int* bl, const unsigned int* bs,
                                          unsigned int tag, u32x4* D, int* mode, bool* dead) {
    const unsigned int ehi = tag << 16;
    if (*mode == 0) {
        for (int it = 0; it < LOC_BULK_BUDGET; ++it) {
            ld32<false>(bl, D);
            if (chk(D, ehi)) return;
        }
        *mode = 1;  // latch
    }
    if (!*dead) {
        unsigned long long t0 = __builtin_amdgcn_s_memrealtime();
        while (true) {
            ld32<true>(bs, D);
            if (chk(D, ehi)) return;
            if (__builtin_amdgcn_s_memrealtime() - t0 > BAIL_TICKS) { *dead = true; break; }
            __builtin_amdgcn_s_sleep(1);
        }
    }
    // poison with bf16 NaN so a protocol flaw fails LOUDLY and fast
    const unsigned int p = ehi | 0x7FC0u;
#pragma unroll
    for (int i = 0; i < 32; ++i) { D[i][0] = p; D[i][1] = p; D[i][2] = p; D[i][3] = p; }
}

// Pack 8 tagged dwords (lo16 = bf16 h) into one MFMA A-fragment.
__device__ __forceinline__ short8 pack_a(const u32x4& d0, const u32x4& d1) {
    u32x4 r;
    r[0] = __builtin_amdgcn_perm(d0[1], d0[0], 0x05040100u);
    r[1] = __builtin_amdgcn_perm(d0[3], d0[2], 0x05040100u);
    r[2] = __builtin_amdgcn_perm(d1[1], d1[0], 0x05040100u);
    r[3] = __builtin_amdgcn_perm(d1[3], d1[2], 0x05040100u);
    return __builtin_bit_cast(short8, r);
}

// Dual publish: plain store (updates own XCD L2 in place -> local readers) +
// sc0 sc1 mirror store (MALL copy -> remote readers). Both fire-and-forget.
__device__ __forceinline__ void st_tag2(unsigned int* pl, unsigned int* ps, unsigned int v) {
    asm volatile("global_store_dword %0, %1, off" :: "v"(pl), "v"(v) : "memory");
    asm volatile("global_store_dword %0, %1, off sc0 sc1" :: "v"(ps), "v"(v) : "memory");
}

// One transition GRU cell (gx = bias only). rc0g = C-row base within group buffer.
__device__ __forceinline__ void trans_cell(const unsigned int* bl, const unsigned int* bs,
                                           const unsigned int* spl, const unsigned int* sps,
                                           unsigned int tag, const unsigned short* ldsp,
                                           int lane, float br, float bz, float bhh,
                                           const float* mm, float* hreg,
                                           unsigned int* wl, unsigned int* wsy,
                                           int rc0g, int hcol, int* mode, bool* dead) {
    poll_tag(spl, sps, tag, mode, dead);
    u32x4 D[32];
    load_htag(bl, bs, tag, D, mode, dead);
    f32x4 acc0 = {0.f, 0.f, 0.f, 0.f}, acc1 = acc0, acc2 = acc0;
#pragma unroll
    for (int ks = 0; ks < 16; ++ks) {
        short8 A = pack_a(D[2 * ks], D[2 * ks + 1]);
        short8 B0 = *(const short8*)(ldsp + (ks * 3 + 0) * 512 + lane * 8);
        short8 B1 = *(const short8*)(ldsp + (ks * 3 + 1) * 512 + lane * 8);
        short8 B2 = *(const short8*)(ldsp + (ks * 3 + 2) * 512 + lane * 8);
        acc0 = __builtin_amdgcn_mfma_f32_16x16x32_bf16(A, B0, acc0, 0, 0, 0);
        acc1 = __builtin_amdgcn_mfma_f32_16x16x32_bf16(A, B1, acc1, 0, 0, 0);
        acc2 = __builtin_amdgcn_mfma_f32_16x16x32_bf16(A, B2, acc2, 0, 0, 0);
    }
    const unsigned int ptag = (tag + 1) << 16;
#pragma unroll
    for (int j = 0; j < 4; ++j) {
        float r = sigm_(acc0[j] + br);
        float z = sigm_(acc1[j] + bz);
        float ht = tanh_(bhh + r * acc2[j]);
        float hn = (1.f - z) * ht + z * hreg[j];
        hn = mm[j] * hn + (1.f - mm[j]) * hreg[j];
        hreg[j] = hn;
        unsigned int v = ptag | (unsigned int)f2bf(hn);
        st_tag2(wl + (rc0g + j) * 512 + hcol, wsy + (rc0g + j) * 512 + hcol, v);
    }
}

// 256 WGs x 128 threads. group = wg % 8 (presumed XCD via round-robin dispatch),
// cs = wg / 8. Group = (dir, batch-quarter of 32 rows). h exchange: XCD-local L2
// via plain stores + sc0 loads; per-wave permanent latch to MALL mirror if the
// group turns out not co-resident (placement-independent correctness).
__global__ __launch_bounds__(128, 1) void rnn_kernel(
    const float* __restrict__ xs, const float* __restrict__ xmask,
    const float* __restrict__ fb, const float* __restrict__ bb,
    const float* __restrict__ ftb, const float* __restrict__ btb,
    float* __restrict__ out, const unsigned short* __restrict__ pack,
    unsigned int* __restrict__ hpub32) {
    extern __shared__ unsigned short lds_u16[];
    const int tid = threadIdx.x;
    const int wg = blockIdx.x;     // 0..255
    const int g = wg & 7;          // group (presumed XCD)
    const int cs = wg >> 3;        // column slice 0..31
    const int dir = g >> 2;        // 0 fwd, 1 bwd
    const int qb = g & 3;          // batch quarter: rows [qb*32, qb*32+32)
    const int w = tid >> 6;        // wave 0..1 -> 16-row block within quarter
    const int lane = tid & 63;

    // Load resident weight packs (Uh, tU0, tU1 slices) into LDS: 3 x 49152 B.
    for (int m = 0; m < 3; ++m) {
        const u32x4* src = (const u32x4*)(pack + (size_t)((dir * 4 + 1 + m) * 32 + cs) * PACK_PER_CS);
        u32x4* dst = (u32x4*)(lds_u16 + m * PACK_PER_CS);
        for (int i = tid; i < PACK_PER_CS / 8; i += 128) dst[i] = src[i];
    }
    __syncthreads();

    const int c16 = lane & 15;
    const int kg = lane >> 4;
    const int rowAg = w * 16 + c16;        // A row within group (0..31)
    const int rc0g = w * 16 + kg * 4;      // C row base within group
    const int rowA = qb * 32 + rowAg;      // global batch row (A)
    const int rowC0 = qb * 32 + rc0g;      // global batch row (C base)
    const int hcol = cs * 16 + c16;

    const float* bsrc = dir ? bb : fb;
    const float* tbsrc = dir ? btb : ftb;
    const float b0r = bsrc[hcol], b0z = bsrc[512 + hcol], b0h = bsrc[1024 + hcol];
    const float b1r = tbsrc[hcol], b1z = tbsrc[512 + hcol], b1h = tbsrc[1024 + hcol];
    const float b2r = tbsrc[TH_ + hcol], b2z = tbsrc[TH_ + 512 + hcol], b2h = tbsrc[TH_ + 1024 + hcol];

    float hreg[4] = {0.f, 0.f, 0.f, 0.f};
    bool dead = false;
    int mode = 0;  // 0 = XCD-local fast path, 1 = MALL mirror (permanent latch)

    const unsigned short* wxpack =
        pack + (size_t)((dir * 4 + 0) * 32 + cs) * PACK_PER_CS + lane * 8;
    // local copy buffers
    unsigned int* lb0 = hpub32 + 0 * BUF_DW + g * GRP_DW;
    unsigned int* lb1 = hpub32 + 1 * BUF_DW + g * GRP_DW;
    // sys (MALL mirror) buffers
    unsigned int* sb0 = hpub32 + COPY_DW + 0 * BUF_DW + g * GRP_DW;
    unsigned int* sb1 = hpub32 + COPY_DW + 1 * BUF_DW + g * GRP_DW;
    const int ka = kg * 8;
    const int aoff = rowAg * 512 + ka;     // dword offset within group buffer
    const float* xrow = xs + (size_t)rowA * L_ * E_ + ka;

    // Cheap-poll sample from OWN wave cohort's rows: wave w samples rows w*16+3
    // (kg=0 last store) / w*16+15 (kg=3 last store), producer cs = lane&31.
    const int sp_hi = lane >> 5;
    const int sp_off = (w * 16 + (sp_hi ? 15 : 3)) * 512 + (lane & 31) * 16 + (sp_hi ? 15 : 0);

    unsigned int gcnt = 0;  // cell counter; read tag = gcnt (0 = pre-zeroed h0), publish gcnt+1
    for (int s = 0; s < L_; ++s) {
        const int t = dir ? (L_ - 1 - s) : s;
        float mm[4];
#pragma unroll
        for (int j = 0; j < 4; ++j) mm[j] = xmask[(rowC0 + j) * L_ + t];

        // ---- CELL 0 x-part (h-independent): overlaps predecessors' publishes ----
        f32x4 acc0 = {0.f, 0.f, 0.f, 0.f}, acc1 = acc0, accgx = acc0;
        {
            const float* xp = xrow + (size_t)t * E_;
#pragma unroll
            for (int ks = 0; ks < 16; ++ks) {
                f32x4 x0 = *(const f32x4*)(xp + ks * 32);
                f32x4 x1 = *(const f32x4*)(xp + ks * 32 + 4);
                short8 A2;
#pragma unroll
                for (int e = 0; e < 4; ++e) {
                    A2[e] = (short)f2bf(x0[e]);
                    A2[4 + e] = (short)f2bf(x1[e]);
                }
                short8 W0 = *(const short8*)(wxpack + (ks * 3 + 0) * 512);
                short8 W1 = *(const short8*)(wxpack + (ks * 3 + 1) * 512);
                short8 W2 = *(const short8*)(wxpack + (ks * 3 + 2) * 512);
                acc0 = __builtin_amdgcn_mfma_f32_16x16x32_bf16(A2, W0, acc0, 0, 0, 0);
                acc1 = __builtin_amdgcn_mfma_f32_16x16x32_bf16(A2, W1, acc1, 0, 0, 0);
                accgx = __builtin_amdgcn_mfma_f32_16x16x32_bf16(A2, W2, accgx, 0, 0, 0);
            }
        }
        // ---- CELL 0 h-part ----
        {
            const unsigned int* bl = ((gcnt & 1) ? lb1 : lb0);
            const unsigned int* bs = ((gcnt & 1) ? sb1 : sb0);
            unsigned int* wl = (gcnt & 1) ? lb0 : lb1;
            unsigned int* wsy = (gcnt & 1) ? sb0 : sb1;
            poll_tag(bl + sp_off, bs + sp_off, gcnt, &mode, &dead);
            u32x4 D[32];
            load_htag(bl + aoff, bs + aoff, gcnt, D, &mode, &dead);
            f32x4 accgh = {0.f, 0.f, 0.f, 0.f};
#pragma unroll
            for (int ks = 0; ks < 16; ++ks) {
                short8 A = pack_a(D[2 * ks], D[2 * ks + 1]);
                short8 B0 = *(const short8*)(lds_u16 + (ks * 3 + 0) * 512 + lane * 8);
                short8 B1 = *(const short8*)(lds_u16 + (ks * 3 + 1) * 512 + lane * 8);
                short8 B2 = *(const short8*)(lds_u16 + (ks * 3 + 2) * 512 + lane * 8);
                acc0 = __builtin_amdgcn_mfma_f32_16x16x32_bf16(A, B0, acc0, 0, 0, 0);
                acc1 = __builtin_amdgcn_mfma_f32_16x16x32_bf16(A, B1, acc1, 0, 0, 0);
                accgh = __builtin_amdgcn_mfma_f32_16x16x32_bf16(A, B2, accgh, 0, 0, 0);
            }
            const unsigned int ptag = (gcnt + 1) << 16;
#pragma unroll
            for (int j = 0; j < 4; ++j) {
                float r = sigm_(acc0[j] + b0r);
                float z = sigm_(acc1[j] + b0z);
                float ht = tanh_(accgx[j] + b0h + r * accgh[j]);
                float hn = (1.f - z) * ht + z * hreg[j];
                hn = mm[j] * hn + (1.f - mm[j]) * hreg[j];
                hreg[j] = hn;
                unsigned int v = ptag | (unsigned int)f2bf(hn);
                st_tag2(wl + (rc0g + j) * 512 + hcol, wsy + (rc0g + j) * 512 + hcol, v);
            }
        }
        gcnt++;
        // ---- CELL 1 (TGRU 0) ----
        trans_cell(((gcnt & 1) ? lb1 : lb0) + aoff, ((gcnt & 1) ? sb1 : sb0) + aoff,
                   ((gcnt & 1) ? lb1 : lb0) + sp_off, ((gcnt & 1) ? sb1 : sb0) + sp_off, gcnt,
                   lds_u16 + PACK_PER_CS, lane, b1r, b1z, b1h, mm, hreg,
                   (gcnt & 1) ? lb0 : lb1, (gcnt & 1) ? sb0 : sb1, rc0g, hcol, &mode, &dead);
        gcnt++;
        // ---- CELL 2 (TGRU 1) ----
        trans_cell(((gcnt & 1) ? lb1 : lb0) + aoff, ((gcnt & 1) ? sb1 : sb0) + aoff,
                   ((gcnt & 1) ? lb1 : lb0) + sp_off, ((gcnt & 1) ? sb1 : sb0) + sp_off, gcnt,
                   lds_u16 + 2 * PACK_PER_CS, lane, b2r, b2z, b2h, mm, hreg,
                   (gcnt & 1) ? lb0 : lb1, (gcnt & 1) ? sb0 : sb1, rc0g, hcol, &mode, &dead);
        gcnt++;
#pragma unroll
        for (int j = 0; j < 4; ++j) {
            out[(size_t)((rowC0 + j) * L_ + t) * 1024 + dir * 512 + hcol] = mm[j] * hreg[j];
        }
    }
}

extern "C" void kernel_launch(void* const* d_in, const int* in_sizes, int n_in, void* d_out,
                              int out_size, void* d_ws, size_t ws_size, hipStream_t stream) {
    (void)in_sizes; (void)n_in; (void)out_size; (void)ws_size;
    const float* xs = (const float*)d_in[0];
    const float* xmask = (const float*)d_in[1];
    const float* fWx = (const float*)d_in[2];
    const float* fUh = (const float*)d_in[3];
    const float* fb = (const float*)d_in[4];
    const float* bWx = (const float*)d_in[5];
    const float* bUh = (const float*)d_in[6];
    const float* bb = (const float*)d_in[7];
    const float* ftU = (const float*)d_in[8];
    const float* ftb = (const float*)d_in[9];
    const float* btU = (const float*)d_in[10];
    const float* btb = (const float*)d_in[11];

    unsigned short* pack = (unsigned short*)d_ws;
    unsigned int* hpub32 = (unsigned int*)((char*)d_ws + HPUB_OFF);

    // zero tagged h buffers, both copies (tag 0 == initial h0 == 0.0f);
    // re-runs on every graph replay
    hipMemsetAsync((char*)d_ws + HPUB_OFF, 0, (size_t)COPY_DW * 2 * 4, stream);

    pack_weights<<<PACK_TOTAL / 256, 256, 0, stream>>>(fWx, fUh, ftU, bWx, bUh, btU, pack);

    hipFuncSetAttribute((const void*)rnn_kernel, hipFuncAttributeMaxDynamicSharedMemorySize,
                        3 * PACK_PER_CS * 2);

    rnn_kernel<<<256, 128, 3 * PACK_PER_CS * 2, stream>>>(xs, xmask, fb, bb, ftb, btb,
                                                          (float*)d_out, pack, hpub32);
}

// Round 8
// 4801.852 us; speedup vs baseline: 1.6349x; 1.3875x over previous
//
#include <hip/hip_runtime.h>
#include <cstdint>

typedef __attribute__((ext_vector_type(8))) short short8;
typedef __attribute__((ext_vector_type(4))) float f32x4;
typedef __attribute__((ext_vector_type(4))) unsigned int u32x4;

#define L_ 256
#define E_ 512
#define H_ 512
#define TH_ 1536

#define PACK_PER_CS 24576                    // ushorts per (mat, cs): 16 ks * 3 f * 64 lanes * 8
#define PACK_TOTAL (8 * 32 * PACK_PER_CS)    // 6,291,456 ushorts
#define HPUB_OFF ((size_t)PACK_TOTAL * 2)    // bytes into ws
#define GRP_DW 16384                         // 32 rows * 512 cols dwords per group per buf
#define BUF_DW (8 * GRP_DW)                  // per buffer: 131,072 dwords (512 KB)

#define BAIL_TICKS 50000000ULL               // ~0.5 s at 100 MHz ref clock (insurance only)
#define FAST_POLL 24                         // sc1 gate attempts before MALL escalation
#define FAST_BULK 3                          // sc1 bulk attempts before MALL escalation

__device__ __forceinline__ unsigned short f2bf(float v) {
    unsigned int u = __builtin_bit_cast(unsigned int, v);
    u += 0x7FFFu + ((u >> 16) & 1u);
    return (unsigned short)(u >> 16);
}
__device__ __forceinline__ float sigm_(float x) { return 1.f / (1.f + __expf(-x)); }
__device__ __forceinline__ float tanh_(float x) {
    float e = __expf(2.f * x);
    return 1.f - 2.f / (e + 1.f);
}

// Pack all 8 weight matrices ([512 x 1536] each) into per-(mat, colslice) MFMA
// fragment layout: elem idx = ((((mat*32+cs)*16 + ks)*3 + f)*64 + lane)*8 + e
// holds U[k][col] with k = ks*32 + (lane>>4)*8 + e, col = f*512 + cs*16 + (lane&15).
__global__ void pack_weights(const float* __restrict__ fWx, const float* __restrict__ fUh,
                             const float* __restrict__ ftU, const float* __restrict__ bWx,
                             const float* __restrict__ bUh, const float* __restrict__ btU,
                             unsigned short* __restrict__ pack) {
    unsigned int idx = blockIdx.x * 256u + threadIdx.x;
    if (idx >= (unsigned)PACK_TOTAL) return;
    int e = idx & 7;
    int l = (idx >> 3) & 63;
    unsigned int r = idx >> 9;
    int f = r % 3; r /= 3;
    int ks = r & 15; r >>= 4;
    int cs = r & 31; r >>= 5;
    int m = r;  // 0..7: {f_Wx, f_Uh, f_tU0, f_tU1, b_Wx, b_Uh, b_tU0, b_tU1}
    int k = ks * 32 + (l >> 4) * 8 + e;
    int col = f * 512 + cs * 16 + (l & 15);
    const float* src;
    switch (m) {
        case 0: src = fWx; break;
        case 1: src = fUh; break;
        case 2: src = ftU; break;
        case 3: src = ftU + H_ * TH_; break;
        case 4: src = bWx; break;
        case 5: src = bUh; break;
        case 6: src = btU; break;
        default: src = btU + H_ * TH_; break;
    }
    pack[idx] = f2bf(src[(size_t)k * TH_ + col]);
}

// Cheap gate, own-cohort rows, monotone >=.
// Ladder: sc1 attempts (bypass L1, read XCD-shared L2 — fast when the group is
// co-XCD) then sc0 sc1 (MALL — proven visible everywhere, rounds 2/4).
// The leading vmcnt(0) also drains this wave's own publish stores.
__device__ __forceinline__ void poll_tag(const unsigned int* sp, unsigned int tag, bool* dead) {
    if (*dead) return;
    for (int it = 0; it < FAST_POLL; ++it) {
        unsigned int v;
        asm volatile("global_load_dword %0, %1, off sc1" : "=v"(v) : "v"(sp) : "memory");
        asm volatile("s_waitcnt vmcnt(0)" ::: "memory");
        __builtin_amdgcn_sched_barrier(0);
        if (__all((int)((v >> 16) >= tag))) return;
    }
    unsigned long long t0 = __builtin_amdgcn_s_memrealtime();
    while (true) {
        unsigned int v;
        asm volatile("global_load_dword %0, %1, off sc0 sc1" : "=v"(v) : "v"(sp) : "memory");
        asm volatile("s_waitcnt vmcnt(0)" ::: "memory");
        __builtin_amdgcn_sched_barrier(0);
        if (__all((int)((v >> 16) >= tag))) return;
        if (__builtin_amdgcn_s_memrealtime() - t0 > BAIL_TICKS) { *dead = true; return; }
    }
}

template <bool SYS>
__device__ __forceinline__ void ld32(const unsigned int* base, u32x4* D) {
#pragma unroll
    for (int i = 0; i < 32; ++i) {
        if constexpr (SYS)
            asm volatile("global_load_dwordx4 %0, %1, off offset:%c2 sc0 sc1"
                         : "=v"(D[i]) : "v"(base), "i"(((i >> 1) * 128) + ((i & 1) * 16)) : "memory");
        else
            asm volatile("global_load_dwordx4 %0, %1, off offset:%c2 sc1"
                         : "=v"(D[i]) : "v"(base), "i"(((i >> 1) * 128) + ((i & 1) * 16)) : "memory");
    }
    asm volatile("s_waitcnt vmcnt(0)" ::: "memory");
    __builtin_amdgcn_sched_barrier(0);
}

__device__ __forceinline__ bool chk(const u32x4* D, unsigned int ehi) {
    unsigned int acc = 0;
#pragma unroll
    for (int i = 0; i < 32; ++i) {
#pragma unroll
        for (int e = 0; e < 4; ++e) acc |= D[i][e] ^ ehi;
    }
    return __all((int)((acc & 0xFFFF0000u) == 0u));
}

// Bulk tagged h load (32x dwordx4 = 128 tagged words/lane), exact-tag verify.
// Rows form a closed wave-index cohort => exact verify is deadlock-free.
// Ladder: sc1 (XCD L2) then sc0 sc1 (MALL). Bail -> NaN poison (insurance).
__device__ __forceinline__ void load_htag(const unsigned int* base, unsigned int tag, u32x4* D,
                                          bool* dead) {
    const unsigned int ehi = tag << 16;
    if (!*dead) {
        for (int it = 0; it < FAST_BULK; ++it) {
            ld32<false>(base, D);
            if (chk(D, ehi)) return;
        }
        unsigned long long t0 = __builtin_amdgcn_s_memrealtime();
        while (true) {
            ld32<true>(base, D);
            if (chk(D, ehi)) return;
            if (__builtin_amdgcn_s_memrealtime() - t0 > BAIL_TICKS) { *dead = true; break; }
        }
    }
    // poison with bf16 NaN so a protocol flaw fails LOUDLY and fast
    const unsigned int p = ehi | 0x7FC0u;
#pragma unroll
    for (int i = 0; i < 32; ++i) { D[i][0] = p; D[i][1] = p; D[i][2] = p; D[i][3] = p; }
}

// Pack 8 tagged dwords (lo16 = bf16 h) into one MFMA A-fragment.
__device__ __forceinline__ short8 pack_a(const u32x4& d0, const u32x4& d1) {
    u32x4 r;
    r[0] = __builtin_amdgcn_perm(d0[1], d0[0], 0x05040100u);
    r[1] = __builtin_amdgcn_perm(d0[3], d0[2], 0x05040100u);
    r[2] = __builtin_amdgcn_perm(d1[1], d1[0], 0x05040100u);
    r[3] = __builtin_amdgcn_perm(d1[3], d1[2], 0x05040100u);
    return __builtin_bit_cast(short8, r);
}

// System-scope publish (write-through to MALL, home L2 updated/invalidated en
// route). Proven visible to sc0sc1 readers (rounds 2/4); fire-and-forget.
__device__ __forceinline__ void st_tag(unsigned int* p, unsigned int v) {
    asm volatile("global_store_dword %0, %1, off sc0 sc1" :: "v"(p), "v"(v) : "memory");
}

// One transition GRU cell (gx = bias only). rc0g = C-row base within group buffer.
__device__ __forceinline__ void trans_cell(const unsigned int* hbase, const unsigned int* spp,
                                           unsigned int tag, const unsigned short* ldsp,
                                           int lane, float br, float bz, float bhh,
                                           const float* mm, float* hreg, unsigned int* hwr,
                                           int rc0g, int hcol, bool* dead) {
    poll_tag(spp, tag, dead);
    u32x4 D[32];
    load_htag(hbase, tag, D, dead);
    f32x4 acc0 = {0.f, 0.f, 0.f, 0.f}, acc1 = acc0, acc2 = acc0;
#pragma unroll
    for (int ks = 0; ks < 16; ++ks) {
        short8 A = pack_a(D[2 * ks], D[2 * ks + 1]);
        short8 B0 = *(const short8*)(ldsp + (ks * 3 + 0) * 512 + lane * 8);
        short8 B1 = *(const short8*)(ldsp + (ks * 3 + 1) * 512 + lane * 8);
        short8 B2 = *(const short8*)(ldsp + (ks * 3 + 2) * 512 + lane * 8);
        acc0 = __builtin_amdgcn_mfma_f32_16x16x32_bf16(A, B0, acc0, 0, 0, 0);
        acc1 = __builtin_amdgcn_mfma_f32_16x16x32_bf16(A, B1, acc1, 0, 0, 0);
        acc2 = __builtin_amdgcn_mfma_f32_16x16x32_bf16(A, B2, acc2, 0, 0, 0);
    }
    const unsigned int ptag = (tag + 1) << 16;
#pragma unroll
    for (int j = 0; j < 4; ++j) {
        float r = sigm_(acc0[j] + br);
        float z = sigm_(acc1[j] + bz);
        float ht = tanh_(bhh + r * acc2[j]);
        float hn = (1.f - z) * ht + z * hreg[j];
        hn = mm[j] * hn + (1.f - mm[j]) * hreg[j];
        hreg[j] = hn;
        st_tag(hwr + (rc0g + j) * 512 + hcol, ptag | (unsigned int)f2bf(hn));
    }
}

// 256 WGs x 128 threads, 1 WG/CU (144 KB LDS). group = wg % 8 (likely one XCD
// under round-robin dispatch — performance heuristic ONLY; the read ladder makes
// correctness placement-independent). cs = wg / 8. Group = (dir, 32-row quarter).
__global__ __launch_bounds__(128, 1) void rnn_kernel(
    const float* __restrict__ xs, const float* __restrict__ xmask,
    const float* __restrict__ fb, const float* __restrict__ bb,
    const float* __restrict__ ftb, const float* __restrict__ btb,
    float* __restrict__ out, const unsigned short* __restrict__ pack,
    unsigned int* __restrict__ hpub32) {
    extern __shared__ unsigned short lds_u16[];
    const int tid = threadIdx.x;
    const int wg = blockIdx.x;     // 0..255
    const int g = wg & 7;          // group (presumed XCD)
    const int cs = wg >> 3;        // column slice 0..31
    const int dir = g >> 2;        // 0 fwd, 1 bwd
    const int qb = g & 3;          // batch quarter: rows [qb*32, qb*32+32)
    const int w = tid >> 6;        // wave 0..1 -> 16-row block within quarter
    const int lane = tid & 63;

    // Load resident weight packs (Uh, tU0, tU1 slices) into LDS: 3 x 49152 B.
    for (int m = 0; m < 3; ++m) {
        const u32x4* src = (const u32x4*)(pack + (size_t)((dir * 4 + 1 + m) * 32 + cs) * PACK_PER_CS);
        u32x4* dst = (u32x4*)(lds_u16 + m * PACK_PER_CS);
        for (int i = tid; i < PACK_PER_CS / 8; i += 128) dst[i] = src[i];
    }
    __syncthreads();

    const int c16 = lane & 15;
    const int kg = lane >> 4;
    const int rowAg = w * 16 + c16;        // A row within group (0..31)
    const int rc0g = w * 16 + kg * 4;      // C row base within group
    const int rowA = qb * 32 + rowAg;      // global batch row (A)
    const int rowC0 = qb * 32 + rc0g;      // global batch row (C base)
    const int hcol = cs * 16 + c16;

    const float* bsrc = dir ? bb : fb;
    const float* tbsrc = dir ? btb : ftb;
    const float b0r = bsrc[hcol], b0z = bsrc[512 + hcol], b0h = bsrc[1024 + hcol];
    const float b1r = tbsrc[hcol], b1z = tbsrc[512 + hcol], b1h = tbsrc[1024 + hcol];
    const float b2r = tbsrc[TH_ + hcol], b2z = tbsrc[TH_ + 512 + hcol], b2h = tbsrc[TH_ + 1024 + hcol];

    float hreg[4] = {0.f, 0.f, 0.f, 0.f};
    bool dead = false;

    const unsigned short* wxpack =
        pack + (size_t)((dir * 4 + 0) * 32 + cs) * PACK_PER_CS + lane * 8;
    unsigned int* hb0 = hpub32 + 0 * BUF_DW + g * GRP_DW;
    unsigned int* hb1 = hpub32 + 1 * BUF_DW + g * GRP_DW;
    const int ka = kg * 8;
    const int aoff = rowAg * 512 + ka;     // dword offset within group buffer
    const float* xrow = xs + (size_t)rowA * L_ * E_ + ka;

    // Cheap-poll sample from OWN wave cohort's rows: wave w samples rows w*16+3
    // (kg=0 last store) / w*16+15 (kg=3 last store), producer cs = lane&31.
    const int sp_hi = lane >> 5;
    const int sp_off = (w * 16 + (sp_hi ? 15 : 3)) * 512 + (lane & 31) * 16 + (sp_hi ? 15 : 0);

    unsigned int gcnt = 0;  // cell counter; read tag = gcnt (0 = pre-zeroed h0), publish gcnt+1
    for (int s = 0; s < L_; ++s) {
        const int t = dir ? (L_ - 1 - s) : s;
        float mm[4];
#pragma unroll
        for (int j = 0; j < 4; ++j) mm[j] = xmask[(rowC0 + j) * L_ + t];

        // ---- CELL 0 x-part (h-independent): overlaps predecessors' publishes ----
        f32x4 acc0 = {0.f, 0.f, 0.f, 0.f}, acc1 = acc0, accgx = acc0;
        {
            const float* xp = xrow + (size_t)t * E_;
#pragma unroll
            for (int ks = 0; ks < 16; ++ks) {
                f32x4 x0 = *(const f32x4*)(xp + ks * 32);
                f32x4 x1 = *(const f32x4*)(xp + ks * 32 + 4);
                short8 A2;
#pragma unroll
                for (int e = 0; e < 4; ++e) {
                    A2[e] = (short)f2bf(x0[e]);
                    A2[4 + e] = (short)f2bf(x1[e]);
                }
                short8 W0 = *(const short8*)(wxpack + (ks * 3 + 0) * 512);
                short8 W1 = *(const short8*)(wxpack + (ks * 3 + 1) * 512);
                short8 W2 = *(const short8*)(wxpack + (ks * 3 + 2) * 512);
                acc0 = __builtin_amdgcn_mfma_f32_16x16x32_bf16(A2, W0, acc0, 0, 0, 0);
                acc1 = __builtin_amdgcn_mfma_f32_16x16x32_bf16(A2, W1, acc1, 0, 0, 0);
                accgx = __builtin_amdgcn_mfma_f32_16x16x32_bf16(A2, W2, accgx, 0, 0, 0);
            }
        }
        // ---- CELL 0 h-part ----
        {
            const unsigned int* hbcur = (gcnt & 1) ? hb1 : hb0;
            unsigned int* hwr = (gcnt & 1) ? hb0 : hb1;
            poll_tag(hbcur + sp_off, gcnt, &dead);
            u32x4 D[32];
            load_htag(hbcur + aoff, gcnt, D, &dead);
            f32x4 accgh = {0.f, 0.f, 0.f, 0.f};
#pragma unroll
            for (int ks = 0; ks < 16; ++ks) {
                short8 A = pack_a(D[2 * ks], D[2 * ks + 1]);
                short8 B0 = *(const short8*)(lds_u16 + (ks * 3 + 0) * 512 + lane * 8);
                short8 B1 = *(const short8*)(lds_u16 + (ks * 3 + 1) * 512 + lane * 8);
                short8 B2 = *(const short8*)(lds_u16 + (ks * 3 + 2) * 512 + lane * 8);
                acc0 = __builtin_amdgcn_mfma_f32_16x16x32_bf16(A, B0, acc0, 0, 0, 0);
                acc1 = __builtin_amdgcn_mfma_f32_16x16x32_bf16(A, B1, acc1, 0, 0, 0);
                accgh = __builtin_amdgcn_mfma_f32_16x16x32_bf16(A, B2, accgh, 0, 0, 0);
            }
            const unsigned int ptag = (gcnt + 1) << 16;
#pragma unroll
            for (int j = 0; j < 4; ++j) {
                float r = sigm_(acc0[j] + b0r);
                float z = sigm_(acc1[j] + b0z);
                float ht = tanh_(accgx[j] + b0h + r * accgh[j]);
                float hn = (1.f - z) * ht + z * hreg[j];
                hn = mm[j] * hn + (1.f - mm[j]) * hreg[j];
                hreg[j] = hn;
                st_tag(hwr + (rc0g + j) * 512 + hcol, ptag | (unsigned int)f2bf(hn));
            }
        }
        gcnt++;
        // ---- CELL 1 (TGRU 0) ----
        trans_cell(((gcnt & 1) ? hb1 : hb0) + aoff, ((gcnt & 1) ? hb1 : hb0) + sp_off, gcnt,
                   lds_u16 + PACK_PER_CS, lane, b1r, b1z, b1h, mm, hreg,
                   (gcnt & 1) ? hb0 : hb1, rc0g, hcol, &dead);
        gcnt++;
        // ---- CELL 2 (TGRU 1) ----
        trans_cell(((gcnt & 1) ? hb1 : hb0) + aoff, ((gcnt & 1) ? hb1 : hb0) + sp_off, gcnt,
                   lds_u16 + 2 * PACK_PER_CS, lane, b2r, b2z, b2h, mm, hreg,
                   (gcnt & 1) ? hb0 : hb1, rc0g, hcol, &dead);
        gcnt++;
#pragma unroll
        for (int j = 0; j < 4; ++j) {
            out[(size_t)((rowC0 + j) * L_ + t) * 1024 + dir * 512 + hcol] = mm[j] * hreg[j];
        }
    }
}

extern "C" void kernel_launch(void* const* d_in, const int* in_sizes, int n_in, void* d_out,
                              int out_size, void* d_ws, size_t ws_size, hipStream_t stream) {
    (void)in_sizes; (void)n_in; (void)out_size; (void)ws_size;
    const float* xs = (const float*)d_in[0];
    const float* xmask = (const float*)d_in[1];
    const float* fWx = (const float*)d_in[2];
    const float* fUh = (const float*)d_in[3];
    const float* fb = (const float*)d_in[4];
    const float* bWx = (const float*)d_in[5];
    const float* bUh = (const float*)d_in[6];
    const float* bb = (const float*)d_in[7];
    const float* ftU = (const float*)d_in[8];
    const float* ftb = (const float*)d_in[9];
    const float* btU = (const float*)d_in[10];
    const float* btb = (const float*)d_in[11];

    unsigned short* pack = (unsigned short*)d_ws;
    unsigned int* hpub32 = (unsigned int*)((char*)d_ws + HPUB_OFF);

    // zero tagged h buffers (tag 0 == initial h0 == 0.0f); re-runs on every graph replay
    hipMemsetAsync((char*)d_ws + HPUB_OFF, 0, (size_t)2 * BUF_DW * 4, stream);

    pack_weights<<<PACK_TOTAL / 256, 256, 0, stream>>>(fWx, fUh, ftU, bWx, bUh, btU, pack);

    hipFuncSetAttribute((const void*)rnn_kernel, hipFuncAttributeMaxDynamicSharedMemorySize,
                        3 * PACK_PER_CS * 2);

    rnn_kernel<<<256, 128, 3 * PACK_PER_CS * 2, stream>>>(xs, xmask, fb, bb, ftb, btb,
                                                          (float*)d_out, pack, hpub32);
}